// Round 2
// baseline (593.729 us; speedup 1.0000x reference)
//
#include <hip/hip_runtime.h>
#include <cstdint>
#include <cstddef>

// ---------------------------------------------------------------------------
// GenEdge: edge = |sum sad*kx| + |sum sad*ky| over 25x25 window of spectral
// angles between 128-dim pixel vectors; normalized by global max.
// Phase 1: f32 -> f16 tiled layout + fp32 norms.
// Phase 2: block = 4 waves = 4 consecutive h rows sharing a rolling,
//          double-buffered B-row slab; banded QK^T via mfma 16x16x32 f16.
// Phase 3: normalize by max, zero 12-px border.
// ---------------------------------------------------------------------------

typedef _Float16 half8 __attribute__((ext_vector_type(8)));
typedef float    f32x4 __attribute__((ext_vector_type(4)));

#define HW   400
#define CCH  128
#define W16  416                 // padded width (26 groups of 16)
#define ROWE (W16*CCH)           // 53248 f16 elements per padded row
#define PAD  12
#define IEND 388                 // interior: [12, 388)
#define HTILE 4                  // h-rows per block (1 per wave)

// f16 cube layout per row: [pg(26)][ks(4)][q(4)][i(16)][j(8)] elements
// offset = pg*2048 + ks*512 + q*128 + i*8 + j
// => frag reads are LDS base + lane*16 B (linear, conflict-free), identical
//    to the order global_load_lds writes (wave-uniform base + lane*16).

__device__ __forceinline__ void g2lds16(const _Float16* g, _Float16* l) {
  void* gg = (void*)g;
  __builtin_amdgcn_global_load_lds(
      (__attribute__((address_space(1))) void*)gg,
      (__attribute__((address_space(3))) void*)l, 16, 0, 0);
}

__device__ __forceinline__ float acos_fast(float x) {
  // Abramowitz-Stegun 4.4.45: |err| <= 6.7e-5 rad on [0,1]; reflect for x<0.
  float ax = fabsf(x);
  float s  = __builtin_amdgcn_sqrtf(1.0f - ax);
  float p  = fmaf(ax, -0.0187292994f, 0.0742610134f);
  p = fmaf(p, ax, -0.2121143967f);
  p = fmaf(p, ax,  1.5707287572f);
  float r = s * p;
  return (x >= 0.0f) ? r : (3.14159265359f - r);
}

// ---------------- Phase 1: convert + norms ----------------
__global__ void cvt_kernel(const float* __restrict__ cube,
                           _Float16* __restrict__ c16,
                           float* __restrict__ norms) {
  int pg = blockIdx.x;        // 0..25 (pg 25 is all-pad)
  int r  = blockIdx.y;        // 0..399
  int t  = threadIdx.x;       // 0..255: t = i*16 + ks*4 + q
  int i  = t >> 4;
  int ks = (t >> 2) & 3;
  int q  = t & 3;
  int px = pg*16 + i;
  float v[8];
  if (px < HW) {
    const float* src = cube + ((size_t)(r*HW + px))*CCH + ks*32 + q*8;
    #pragma unroll
    for (int j = 0; j < 8; ++j) v[j] = src[j];
  } else {
    #pragma unroll
    for (int j = 0; j < 8; ++j) v[j] = 0.f;
  }
  half8 hv;
  float ss = 0.f;
  #pragma unroll
  for (int j = 0; j < 8; ++j) { hv[j] = (_Float16)v[j]; ss += v[j]*v[j]; }
  *(half8*)(c16 + (size_t)r*ROWE + pg*2048 + ks*512 + q*128 + i*8) = hv;
  #pragma unroll
  for (int m = 1; m < 16; m <<= 1) ss += __shfl_xor(ss, m);
  if ((t & 15) == 0) norms[r*W16 + px] = (px < HW) ? sqrtf(ss) : 0.f;
}

// ---------------- Phase 2: banded MFMA + SAD accumulation ----------------
__global__ __launch_bounds__(256, 2) void edge_kernel(
    const _Float16* __restrict__ c16, const float* __restrict__ norms,
    float* __restrict__ edge, unsigned* __restrict__ gmax) {
  __shared__ _Float16 slab[2][6*2048];   // 2 x 24576 B, double-buffered

  const int wb  = blockIdx.x;            // 0..5   (w-block)
  const int h0  = blockIdx.y*HTILE + PAD;
  const int tid = threadIdx.x;
  const int wv  = tid >> 6;              // wave id 0..3 -> h = h0+wv
  const int l   = tid & 63;
  const int c   = l & 15, q = l >> 4;
  const int h   = h0 + wv;
  const int w0  = PAD + 64*wb;
  const int g0  = 4*wb;                  // first staged pixel-group

  // A-frags: center pixels of row h.  A[m=lane&15][k=q*8+j]
  half8 A[4][4];
  #pragma unroll
  for (int t = 0; t < 4; ++t) {
    int px = w0 + 16*t + c;              // <= 395 < 400
    const _Float16* p = c16 + (size_t)h*ROWE + (px >> 4)*2048 + q*128 + (px & 15)*8;
    #pragma unroll
    for (int ks = 0; ks < 4; ++ks)
      A[t][ks] = *(const half8*)(p + ks*512);
  }
  float nc[4][4];
  #pragma unroll
  for (int t = 0; t < 4; ++t)
    #pragma unroll
    for (int rr = 0; rr < 4; ++rr)
      nc[t][rr] = norms[h*W16 + w0 + 16*t + 4*q + rr];

  float gx[4][4], gy[4][4];
  #pragma unroll
  for (int t = 0; t < 4; ++t)
    #pragma unroll
    for (int rr = 0; rr < 4; ++rr) { gx[t][rr] = 0.f; gy[t][rr] = 0.f; }

  const int rlo = h0 - PAD;              // >= 0
  const int rhi = h0 + HTILE - 1 + PAD;  // <= 399

  // prologue: stage slab for rlo into buf 0 (all 256 threads, 6 chunks each)
  {
    const _Float16* rowB = c16 + (size_t)rlo*ROWE + g0*2048;
    #pragma unroll
    for (int k = 0; k < 6; ++k) {
      int ci = k*256 + tid;              // 1536 x 16B chunks
      g2lds16(rowB + ci*8, slab[0] + ci*8);
    }
  }
  __syncthreads();

  int buf = 0;
  #pragma unroll 1
  for (int r = rlo; r <= rhi; ++r) {
    // issue async stage of next slab into the other buffer
    if (r < rhi) {
      const _Float16* rowB = c16 + (size_t)(r+1)*ROWE + g0*2048;
      _Float16* dst = slab[buf ^ 1];
      #pragma unroll
      for (int k = 0; k < 6; ++k) {
        int ci = k*256 + tid;
        g2lds16(rowB + ci*8, dst + ci*8);
      }
    }

    const int di = r - h + PAD;          // this wave's row offset
    if (di >= 0 && di <= 24) {
      const float* nr = norms + r*W16 + 64*wb;
      float ns[6];
      #pragma unroll
      for (int n = 0; n < 6; ++n) ns[n] = nr[16*n + c];

      f32x4 acc[4][3];
      #pragma unroll
      for (int t = 0; t < 4; ++t)
        #pragma unroll
        for (int d = 0; d < 3; ++d)
          acc[t][d] = (f32x4){0.f, 0.f, 0.f, 0.f};

      const _Float16* sb = slab[buf];
      #pragma unroll
      for (int ks = 0; ks < 4; ++ks) {
        half8 B[6];
        #pragma unroll
        for (int n = 0; n < 6; ++n)      // linear, conflict-free ds_read_b128
          B[n] = *(const half8*)(sb + n*2048 + ks*512 + l*8);
        #pragma unroll
        for (int t = 0; t < 4; ++t)
          #pragma unroll
          for (int d = 0; d < 3; ++d)    // band: M-tile t uses N-tiles t..t+2
            acc[t][d] = __builtin_amdgcn_mfma_f32_16x16x32_f16(
                A[t][ks], B[t + d], acc[t][d], 0, 0, 0);
      }

      const int ii  = (di <= 12) ? di : 24 - di;
      const int sdi = (di > 12) - (di < 12);
      #pragma unroll
      for (int t = 0; t < 4; ++t) {
        #pragma unroll
        for (int d = 0; d < 3; ++d) {
          const float nn = ns[t + d];
          #pragma unroll
          for (int rr = 0; rr < 4; ++rr) {
            float numer = acc[t][d][rr];
            int   dj    = 16*d + c - (4*q + rr);     // s - w + 12
            float denom = nc[t][rr]*nn + 1e-4f;
            float ratio = numer * __builtin_amdgcn_rcpf(denom);
            ratio = fminf(fmaxf(ratio, -0.999999f), 0.999999f);
            float sad = acos_fast(ratio);
            bool  ok  = (dj >= 0) && (dj <= 24);
            int   sdj = (dj > 12) - (dj < 12);
            int   mnj = (dj < 24 - dj) ? dj : 24 - dj;
            float kx  = ok ? (float)(dj - 12 + sdj*ii)  : 0.f;
            float ky  = ok ? (float)(di - 12 + sdi*mnj) : 0.f;
            gx[t][rr] = fmaf(sad, kx, gx[t][rr]);
            gy[t][rr] = fmaf(sad, ky, gy[t][rr]);
          }
        }
      }
    }
    __syncthreads();                     // readers done + next slab landed
    buf ^= 1;
  }

  // cross-lane reduce over c (partial C-columns) via LDS scratch (slab free)
  float* red = (float*)slab + wv*2048;   // 8 KB per wave, 32 KB total
  #pragma unroll
  for (int t = 0; t < 4; ++t)
    #pragma unroll
    for (int rr = 0; rr < 4; ++rr) {
      int p = t*16 + q*4 + rr;
      red[p*16 + c]        = gx[t][rr];
      red[1024 + p*16 + c] = gy[t][rr];
    }
  __syncthreads();
  {
    int p = l;
    float sgx = 0.f, sgy = 0.f;
    #pragma unroll
    for (int cc = 0; cc < 16; ++cc) {
      sgx += red[p*16 + cc];
      sgy += red[1024 + p*16 + cc];
    }
    float e = fabsf(sgx) + fabsf(sgy);
    int tt = p >> 4, qq = (p >> 2) & 3, rr2 = p & 3;
    int w  = w0 + 16*tt + 4*qq + rr2;
    if (w < IEND) edge[h*HW + w] = e;
    else          e = 0.f;               // over-computed right-edge cols
    #pragma unroll
    for (int off = 1; off < 64; off <<= 1) e = fmaxf(e, __shfl_xor(e, off));
    if (l == 0) atomicMax(gmax, __float_as_uint(e));
  }
}

// ---------------- Phase 3: normalize ----------------
__global__ void norm_kernel(const float* __restrict__ edge,
                            const unsigned* __restrict__ gmax,
                            float* __restrict__ out) {
  int idx = blockIdx.x*256 + threadIdx.x;
  if (idx >= HW*HW) return;
  int hh = idx / HW;
  int ww = idx - hh*HW;
  float mv = __uint_as_float(*gmax);
  float v = 0.f;
  if (hh >= PAD && hh < IEND && ww >= PAD && ww < IEND)
    v = edge[idx] / mv;
  out[idx] = v;
}

// ---------------- launch ----------------
extern "C" void kernel_launch(void* const* d_in, const int* in_sizes, int n_in,
                              void* d_out, int out_size, void* d_ws, size_t ws_size,
                              hipStream_t stream) {
  const float* cube = (const float*)d_in[0];   // (1,400,400,128) f32
  char* ws = (char*)d_ws;
  _Float16* c16   = (_Float16*)(ws);                    // 42,598,400 B
  float*    norms = (float*)(ws + 42598400);            //    665,600 B
  float*    edgeb = (float*)(ws + 43264000);            //    640,000 B
  unsigned* gmax  = (unsigned*)(ws + 43904000);         //          4 B

  hipMemsetAsync(gmax, 0, 4, stream);
  cvt_kernel<<<dim3(26, 400), 256, 0, stream>>>(cube, c16, norms);
  edge_kernel<<<dim3(6, 94), 256, 0, stream>>>(c16, norms, edgeb, gmax);
  norm_kernel<<<(HW*HW + 255)/256, 256, 0, stream>>>(edgeb, gmax, (float*)d_out);
}

// Round 3
// 284.619 us; speedup vs baseline: 2.0860x; 2.0860x over previous
//
#include <hip/hip_runtime.h>
#include <cstdint>
#include <cstddef>

// ---------------------------------------------------------------------------
// GenEdge: edge = |sum sad*kx| + |sum sad*ky| over 25x25 window of spectral
// angles between 128-dim pixel vectors; normalized by global max.
// R3 design:
//   Phase 1: f32 -> UNIT-NORM f16 tiled layout (ratio = A_hat . B_hat, so the
//            epilogue needs no rcp and no norms loads; the +1e-4 regularizer
//            perturbs ratio by ~2.4e-6 << tolerance; self-term has weight 0).
//   Phase 2: 1 wave per (h, 64-col) block, 2256 blocks. NO LDS staging:
//            B-frags are loaded directly from global (frag-native layout is
//            linear in memory -> perfectly coalesced dwordx4). No barriers.
//            Final reduction via shfl_xor -> zero LDS -> max occupancy.
//            XCD swizzle gives each XCD a contiguous h-band for L2 locality.
//   Phase 3: normalize by max, zero 12-px border.
// ---------------------------------------------------------------------------

typedef _Float16 half8 __attribute__((ext_vector_type(8)));
typedef float    f32x4 __attribute__((ext_vector_type(4)));

#define HW   400
#define CCH  128
#define W16  416                 // padded width (26 groups of 16)
#define ROWE (W16*CCH)           // 53248 f16 elements per padded row
#define PAD  12
#define IEND 388                 // interior: [12, 388)

// f16 cube layout per row: [pg(26)][ks(4)][q(4)][i(16)][j(8)] elements
// offset = pg*2048 + ks*512 + q*128 + i*8 + j
// => a wave's B-frag load for (group, ks) is base + lane*16 B: one coalesced
//    global_load_dwordx4 per (n, ks). No LDS round-trip needed.

__device__ __forceinline__ float acos_fast(float x) {
  // Abramowitz-Stegun 4.4.45: |err| <= 6.7e-5 rad on [0,1]; reflect for x<0.
  float ax = fabsf(x);
  float s  = __builtin_amdgcn_sqrtf(1.0f - ax);
  float p  = fmaf(ax, -0.0187292994f, 0.0742610134f);
  p = fmaf(p, ax, -0.2121143967f);
  p = fmaf(p, ax,  1.5707287572f);
  float r = s * p;
  return (x >= 0.0f) ? r : (3.14159265359f - r);
}

// ---------------- Phase 1: convert + normalize ----------------
__global__ void cvt_kernel(const float* __restrict__ cube,
                           _Float16* __restrict__ c16) {
  int pg = blockIdx.x;        // 0..25 (pg 25 is all-pad)
  int r  = blockIdx.y;        // 0..399
  int t  = threadIdx.x;       // 0..255: t = i*16 + ks*4 + q
  int i  = t >> 4;
  int ks = (t >> 2) & 3;
  int q  = t & 3;
  int px = pg*16 + i;
  float v[8];
  if (px < HW) {
    const float* src = cube + ((size_t)(r*HW + px))*CCH + ks*32 + q*8;
    #pragma unroll
    for (int j = 0; j < 8; ++j) v[j] = src[j];
  } else {
    #pragma unroll
    for (int j = 0; j < 8; ++j) v[j] = 0.f;
  }
  float ss = 0.f;
  #pragma unroll
  for (int j = 0; j < 8; ++j) ss += v[j]*v[j];
  // butterfly over the 16 lanes sharing pixel i (lane bits 0..3 = (ks,q))
  #pragma unroll
  for (int m = 1; m < 16; m <<= 1) ss += __shfl_xor(ss, m);
  float sc = (ss > 0.f) ? rsqrtf(ss) : 0.f;
  half8 hv;
  #pragma unroll
  for (int j = 0; j < 8; ++j) hv[j] = (_Float16)(v[j]*sc);
  *(half8*)(c16 + (size_t)r*ROWE + pg*2048 + ks*512 + q*128 + i*8) = hv;
}

// ---------------- Phase 2: banded MFMA + SAD accumulation ----------------
__global__ __launch_bounds__(64, 2) void edge_kernel(
    const _Float16* __restrict__ c16,
    float* __restrict__ edge, unsigned* __restrict__ gmax) {
  // XCD swizzle: blockIdx round-robins XCDs (id % 8). Give XCD x the
  // contiguous work band g = x*282 + (id>>3) so its L2 sees a ~50-row window.
  const int id = blockIdx.x;             // 0..2255 = 8 * 282
  const int g  = (id & 7)*282 + (id >> 3);
  const int h  = g / 6 + PAD;            // 12..387
  const int wb = g - (g/6)*6;            // 0..5
  const int l  = threadIdx.x;
  const int c  = l & 15, q = l >> 4;
  const int w0 = PAD + 64*wb;
  const int g0 = 4*wb;                   // first B pixel-group

  // A-frags: center pixels of row h.  A[m=lane&15][k=q*8+j]
  half8 A[4][4];
  #pragma unroll
  for (int t = 0; t < 4; ++t) {
    int px = w0 + 16*t + c;              // <= 395 < 400
    const _Float16* p = c16 + (size_t)h*ROWE + (px >> 4)*2048 + q*128 + (px & 15)*8;
    #pragma unroll
    for (int ks = 0; ks < 4; ++ks)
      A[t][ks] = *(const half8*)(p + ks*512);
  }

  // per-lane weight-slot constants (di-invariant): slot j = d*4 + rr
  float base_m[12], sdj_m[12], mnj_m[12], one_m[12];
  #pragma unroll
  for (int d = 0; d < 3; ++d)
    #pragma unroll
    for (int rr = 0; rr < 4; ++rr) {
      int j  = d*4 + rr;
      int dj = 16*d + c - (4*q + rr);    // s - w + 12, in [-15, 47]
      bool ok = (dj >= 0) && (dj <= 24);
      int  sdj = (dj > 12) - (dj < 12);
      int  mnj = (dj < 24 - dj) ? dj : 24 - dj;
      base_m[j] = ok ? (float)(dj - 12) : 0.f;
      sdj_m[j]  = ok ? (float)sdj       : 0.f;
      mnj_m[j]  = ok ? (float)mnj       : 0.f;
      one_m[j]  = ok ? 1.f              : 0.f;
    }

  float gx[4][4], gy[4][4];
  #pragma unroll
  for (int t = 0; t < 4; ++t)
    #pragma unroll
    for (int rr = 0; rr < 4; ++rr) { gx[t][rr] = 0.f; gy[t][rr] = 0.f; }

  #pragma unroll 1
  for (int di = 0; di < 25; ++di) {
    const int r = h + di - PAD;          // 0..399
    const _Float16* rowB = c16 + (size_t)r*ROWE + g0*2048;

    f32x4 acc[4][3];
    #pragma unroll
    for (int t = 0; t < 4; ++t)
      #pragma unroll
      for (int d = 0; d < 3; ++d)
        acc[t][d] = (f32x4){0.f, 0.f, 0.f, 0.f};

    #pragma unroll
    for (int ks = 0; ks < 4; ++ks) {
      half8 B[6];
      #pragma unroll
      for (int n = 0; n < 6; ++n)        // coalesced global dwordx4
        B[n] = *(const half8*)(rowB + n*2048 + ks*512 + l*8);
      #pragma unroll
      for (int t = 0; t < 4; ++t)
        #pragma unroll
        for (int d = 0; d < 3; ++d)      // band: M-tile t uses N-tiles t..t+2
          acc[t][d] = __builtin_amdgcn_mfma_f32_16x16x32_f16(
              A[t][ks], B[t + d], acc[t][d], 0, 0, 0);
    }

    // per-di weights: kx = base + sdj*ii ; ky = (di-12)*ok + sdi*mnj
    const float ii  = (float)((di <= 12) ? di : 24 - di);
    const float sdi = (float)((di > 12) - (di < 12));
    const float dif = (float)(di - 12);
    float kx[12], ky[12];
    #pragma unroll
    for (int j = 0; j < 12; ++j) {
      kx[j] = fmaf(sdj_m[j], ii, base_m[j]);
      ky[j] = fmaf(sdi, mnj_m[j], dif*one_m[j]);
    }

    #pragma unroll
    for (int t = 0; t < 4; ++t)
      #pragma unroll
      for (int d = 0; d < 3; ++d)
        #pragma unroll
        for (int rr = 0; rr < 4; ++rr) {
          int   j     = d*4 + rr;
          float ratio = acc[t][d][rr];   // already cos (unit vectors)
          ratio = fminf(fmaxf(ratio, -0.999999f), 0.999999f);
          float sad = acos_fast(ratio);
          gx[t][rr] = fmaf(sad, kx[j], gx[t][rr]);
          gy[t][rr] = fmaf(sad, ky[j], gy[t][rr]);
        }
  }

  // reduce over c (lane bits 0..3) via butterfly; writers: lanes c == rr
  float e = 0.f;
  #pragma unroll
  for (int t = 0; t < 4; ++t)
    #pragma unroll
    for (int rr = 0; rr < 4; ++rr) {
      float sgx = gx[t][rr], sgy = gy[t][rr];
      #pragma unroll
      for (int m = 1; m < 16; m <<= 1) {
        sgx += __shfl_xor(sgx, m);
        sgy += __shfl_xor(sgy, m);
      }
      if (c == rr) {
        int w = w0 + 16*t + 4*q + rr;
        float v = fabsf(sgx) + fabsf(sgy);
        if (w < IEND) { edge[h*HW + w] = v; e = fmaxf(e, v); }
      }
    }
  #pragma unroll
  for (int off = 1; off < 64; off <<= 1) e = fmaxf(e, __shfl_xor(e, off));
  if (l == 0) atomicMax(gmax, __float_as_uint(e));  // e >= 0: uint order ok
}

// ---------------- Phase 3: normalize ----------------
__global__ void norm_kernel(const float* __restrict__ edge,
                            const unsigned* __restrict__ gmax,
                            float* __restrict__ out) {
  int idx = blockIdx.x*256 + threadIdx.x;
  if (idx >= HW*HW) return;
  int hh = idx / HW;
  int ww = idx - hh*HW;
  float mv = __uint_as_float(*gmax);
  float v = 0.f;
  if (hh >= PAD && hh < IEND && ww >= PAD && ww < IEND)
    v = edge[idx] / mv;
  out[idx] = v;
}

// ---------------- launch ----------------
extern "C" void kernel_launch(void* const* d_in, const int* in_sizes, int n_in,
                              void* d_out, int out_size, void* d_ws, size_t ws_size,
                              hipStream_t stream) {
  const float* cube = (const float*)d_in[0];   // (1,400,400,128) f32
  char* ws = (char*)d_ws;
  _Float16* c16   = (_Float16*)(ws);                    // 42,598,400 B
  float*    edgeb = (float*)(ws + 42598400);            //    640,000 B
  unsigned* gmax  = (unsigned*)(ws + 43238400);         //          4 B

  hipMemsetAsync(gmax, 0, 4, stream);
  cvt_kernel<<<dim3(26, 400), 256, 0, stream>>>(cube, c16);
  edge_kernel<<<2256, 64, 0, stream>>>(c16, edgeb, gmax);
  norm_kernel<<<(HW*HW + 255)/256, 256, 0, stream>>>(edgeb, gmax, (float*)d_out);
}